// Round 3
// baseline (499.182 us; speedup 1.0000x reference)
//
#include <hip/hip_runtime.h>
#include <hip/hip_bf16.h>

// Performer-style linear attention: B=4, S=8192, H=768, NH=12, HD=64, M=64.
// Round 7:
//  - gemm_qkv: persistent 128x128/BK64/4-wave blocks, 64 KB LDS -> 2 blocks/CU
//    (cross-block MFMA/LDS overlap), grid=512, block b owns mt=b&255 (A panel
//    L2-resident) and sweeps 9 nt tiles; vmcnt ledger continuous across tiles
//    (next tile's first stage issues before the epilogue -> prologue hidden).
//  - ctx_out: fused (qp@kv)/norm + out-projection. ctx[64][768] built in LDS
//    (qp/kv fragments direct from L2, no staging), then K=768 GEMM vs WoT with
//    counted-vmcnt dbuf staging. Kills the 100 MB ctx round-trip + a launch.
// Pipeline:
//   K0 zero kvT; K1 cvt hs->bf16; K2 fold P into Wq/Wk; K3 build cat weights
//   K4 gemm_qkv (persistent) -> qp row-major, kpT/vT transposed
//   K5 kv_accum_mfma -> kvT fp32 (row 64 = ksum)
//   K6 cvt kvT -> kvH bf16
//   K7 ctx_out -> out fp32

#define S_    8192
#define H_    768
#define NH_   12
#define EPS_  1e-6f

typedef unsigned short U16;
typedef short bf16x8 __attribute__((ext_vector_type(8)));
typedef float f32x4  __attribute__((ext_vector_type(4)));

__device__ __forceinline__ U16 f2b(float x) {            // fp32 -> bf16 RNE
  unsigned u = __float_as_uint(x);
  return (U16)((u + 0x7fffu + ((u >> 16) & 1u)) >> 16);
}
__device__ __forceinline__ float b2f(U16 h) {
  return __uint_as_float(((unsigned)h) << 16);
}
__device__ __forceinline__ void gl2lds16(const void* g, void* l) {
  __builtin_amdgcn_global_load_lds(
      (const __attribute__((address_space(1))) void*)g,
      (__attribute__((address_space(3))) void*)l, 16, 0, 0);
}

// ---------- K0: zero scratch ----------
__global__ void zero_f32(float* __restrict__ p, int n) {
  int i = blockIdx.x * 256 + threadIdx.x;
  if (i < n) p[i] = 0.f;
}

// ---------- K1: fp32 -> bf16 ----------
__global__ void cvt_f32_bf16(const float* __restrict__ src, U16* __restrict__ hi, int n4) {
  int i = blockIdx.x * 256 + threadIdx.x;
  if (i >= n4) return;
  float4 x = ((const float4*)src)[i];
  ushort4 h;
  h.x = f2b(x.x); h.y = f2b(x.y); h.z = f2b(x.z); h.w = f2b(x.w);
  ((ushort4*)hi)[i] = h;
}

// ---------- K2: fold P into Wq / Wk (and biases) ----------
__global__ void fold_proj(const float* __restrict__ Wq, const float* __restrict__ bq,
                          const float* __restrict__ Wk, const float* __restrict__ bk,
                          const float* __restrict__ P,
                          float* __restrict__ Wqp, float* __restrict__ bqp,
                          float* __restrict__ Wkp, float* __restrict__ bkp) {
  __shared__ float Pl[64 * 64];
  __shared__ float WL[4 * 64];
  int h = blockIdx.y, kc = blockIdx.x, tid = threadIdx.x;
  const float* W  = blockIdx.z ? Wk : Wq;
  const float* bb = blockIdx.z ? bk : bq;
  float* Wout = blockIdx.z ? Wkp : Wqp;
  float* bout = blockIdx.z ? bkp : bqp;
  const float4* P4 = (const float4*)(P + (size_t)h * 4096);
#pragma unroll
  for (int i = 0; i < 4; ++i) ((float4*)Pl)[tid + i * 256] = P4[tid + i * 256];
  WL[tid] = W[(size_t)(kc * 4 + (tid >> 6)) * H_ + h * 64 + (tid & 63)];
  __syncthreads();
  int kl = tid >> 6, m = tid & 63;
  float acc = 0.f;
#pragma unroll
  for (int d = 0; d < 64; ++d) acc += WL[kl * 64 + d] * Pl[d * 64 + m];
  Wout[(size_t)(kc * 4 + kl) * H_ + h * 64 + m] = acc;
  if (kc == 0 && tid < 64) {
    float a2 = 0.f;
    for (int d = 0; d < 64; ++d) a2 += bb[h * 64 + d] * Pl[d * 64 + tid];
    bout[h * 64 + tid] = a2;
  }
}

// ---------- K3: build B^T-layout weights as bf16 ----------
__global__ void build_cat(const float* __restrict__ Wqp, const float* __restrict__ Wkp,
                          const float* __restrict__ Wv,  const float* __restrict__ Wo,
                          U16* __restrict__ WcatH, U16* __restrict__ WoTH) {
  int k = blockIdx.x * 256 + threadIdx.x;
  int r = blockIdx.y;
  float v; U16* dh; size_t off;
  if (r < 768)       { v = Wqp[(size_t)k * H_ + r];          off = (size_t)r * H_ + k;          dh = WcatH; }
  else if (r < 1536) { v = Wkp[(size_t)k * H_ + (r - 768)];  off = (size_t)r * H_ + k;          dh = WcatH; }
  else if (r < 2304) { v = Wv [(size_t)k * H_ + (r - 1536)]; off = (size_t)r * H_ + k;          dh = WcatH; }
  else               { v = Wo [(size_t)k * H_ + (r - 2304)]; off = (size_t)(r - 2304) * H_ + k; dh = WoTH; }
  dh[off] = f2b(v);
}

__global__ void build_bias(const float* __restrict__ bqp, const float* __restrict__ bkp,
                           const float* __restrict__ bv, float* __restrict__ biasC) {
  int i = blockIdx.x * 256 + threadIdx.x;
  if (i >= 2304) return;
  biasC[i] = i < 768 ? bqp[i] : (i < 1536 ? bkp[i - 768] : bv[i - 1536]);
}

// ---------- K4: persistent 128x128 bf16 GEMM + fused maxexp epilogue ----------
// 512 blocks (2/CU), 256 threads (4 waves, 2x2), BK=64, dbuf 64 KB LDS.
// Block b: mt = b&255 fixed (A panel reused), nt = (b>>8) + 2*jj, jj=0..8.
// Continuous depth-1 vmcnt(8) ledger across tile boundaries; epilogue overlaps
// next tile's first stage.
__global__ __launch_bounds__(256, 2) void gemm_qkv(
    const U16* __restrict__ Ahi, const U16* __restrict__ Bhi,
    const float* __restrict__ bias,
    U16* __restrict__ qp, U16* __restrict__ kpT, U16* __restrict__ vT) {
  __shared__ __align__(16) U16 Us[32768];            // [buf][A/B][128][64] bf16
  const int tid = threadIdx.x, w = tid >> 6, lane = tid & 63;
  const int quad = lane >> 4, l16 = lane & 15;
  const int b = blockIdx.x;                          // 512 persistent blocks
  const int mt = b & 255, nt0 = b >> 8;
  const int rowA0 = mt * 128;
  const int wm = w & 1, wn = w >> 1;
  // staging: 16 chunks of 8 rows; thread handles c = w*4+t (A and B)
  const U16* srcA[4];
  int rowBl[4];
  unsigned ldsc[4];
  const int kch = ((lane & 7) ^ (lane >> 3)) * 8;    // pre-swizzled src chunk
#pragma unroll
  for (int t = 0; t < 4; ++t) {
    int c = w * 4 + t;
    int row = c * 8 + (lane >> 3);
    srcA[t] = Ahi + (size_t)(rowA0 + row) * H_ + kch;
    rowBl[t] = row;
    ldsc[t] = (unsigned)c * 512;                     // U16 offset (1 KB/chunk)
  }
  auto stage = [&](int jn, int tn, int bi) {
    const int colB = (nt0 + 2 * jn) * 128;
    unsigned ub = (unsigned)bi * 16384u;
#pragma unroll
    for (int t = 0; t < 4; ++t) {
      gl2lds16(srcA[t] + tn * 64, &Us[ub + ldsc[t]]);
      gl2lds16(Bhi + (size_t)(colB + rowBl[t]) * H_ + tn * 64 + kch,
               &Us[ub + 8192u + ldsc[t]]);
    }
  };

  stage(0, 0, 0);
  for (int jj = 0; jj < 9; ++jj) {
    const int colB0 = (nt0 + 2 * jj) * 128;
    f32x4 acc[4][4] = {};
    for (int t = 0; t < 12; ++t) {
      const bool more = !(jj == 8 && t == 11);
      if (more) {
        if (t < 11) stage(jj, t + 1, (t + 1) & 1);
        else        stage(jj + 1, 0, 0);
        asm volatile("s_waitcnt vmcnt(8)" ::: "memory");
      } else {
        asm volatile("s_waitcnt vmcnt(0)" ::: "memory");
      }
      __builtin_amdgcn_sched_barrier(0);
      __builtin_amdgcn_s_barrier();
      __builtin_amdgcn_sched_barrier(0);
      const unsigned ab = (unsigned)(t & 1) * 16384u;
      bf16x8 ah[4][2], bh[4][2];
#pragma unroll
      for (int i = 0; i < 4; ++i)
#pragma unroll
        for (int ks = 0; ks < 2; ++ks)
          ah[i][ks] = *(const bf16x8*)&Us[ab +
              (unsigned)((wm * 64 + i * 16 + l16) * 64 +
                         (((ks * 4 + quad) ^ (l16 & 7)) * 8))];
#pragma unroll
      for (int j = 0; j < 4; ++j)
#pragma unroll
        for (int ks = 0; ks < 2; ++ks)
          bh[j][ks] = *(const bf16x8*)&Us[ab + 8192u +
              (unsigned)((wn * 64 + j * 16 + l16) * 64 +
                         (((ks * 4 + quad) ^ (l16 & 7)) * 8))];
      asm volatile("s_waitcnt lgkmcnt(0)" ::: "memory");
      __builtin_amdgcn_sched_barrier(0);
      __builtin_amdgcn_s_setprio(1);
#pragma unroll
      for (int ks = 0; ks < 2; ++ks)
#pragma unroll
        for (int j = 0; j < 4; ++j)
#pragma unroll
          for (int i = 0; i < 4; ++i)
            acc[i][j] = __builtin_amdgcn_mfma_f32_16x16x32_bf16(
                ah[i][ks], bh[j][ks], acc[i][j], 0, 0, 0);
      __builtin_amdgcn_s_setprio(0);
      __builtin_amdgcn_sched_barrier(0);
      __builtin_amdgcn_s_barrier();
      __builtin_amdgcn_sched_barrier(0);
    }
    // ---- epilogue for this tile (doesn't touch LDS; overlaps next stage)
    const int col64 = colB0 + wn * 64;
    float bj[4];
#pragma unroll
    for (int j = 0; j < 4; ++j) bj[j] = bias[col64 + j * 16 + l16];
    if (col64 < 768) {                            // q logits -> row-major qp
      const int h = col64 >> 6;
#pragma unroll
      for (int i = 0; i < 4; ++i) {
#pragma unroll
        for (int r = 0; r < 4; ++r) {
          int row = rowA0 + wm * 64 + i * 16 + quad * 4 + r;
          float v0 = acc[i][0][r] + bj[0], v1 = acc[i][1][r] + bj[1];
          float v2 = acc[i][2][r] + bj[2], v3 = acc[i][3][r] + bj[3];
          float mx = fmaxf(fmaxf(v0, v1), fmaxf(v2, v3));
          mx = fmaxf(mx, __shfl_xor(mx, 1));
          mx = fmaxf(mx, __shfl_xor(mx, 2));
          mx = fmaxf(mx, __shfl_xor(mx, 4));
          mx = fmaxf(mx, __shfl_xor(mx, 8));
          int bb = row >> 13, s = row & 8191;
          size_t base = ((size_t)(bb * NH_ + h) * S_ + s) * 64 + l16;
          qp[base +  0] = f2b(__expf(v0 - mx));
          qp[base + 16] = f2b(__expf(v1 - mx));
          qp[base + 32] = f2b(__expf(v2 - mx));
          qp[base + 48] = f2b(__expf(v3 - mx));
        }
      }
    } else {                                      // k (exp) or v -> transposed
      const int isv = col64 >= 1536;
      const int h = (col64 - (isv ? 1536 : 768)) >> 6;
      U16* dstT = isv ? vT : kpT;
#pragma unroll
      for (int i = 0; i < 4; ++i) {
        float er[4][4];                           // [j][r]
#pragma unroll
        for (int r = 0; r < 4; ++r) {
          float v0 = acc[i][0][r] + bj[0], v1 = acc[i][1][r] + bj[1];
          float v2 = acc[i][2][r] + bj[2], v3 = acc[i][3][r] + bj[3];
          if (!isv) {
            float mx = fmaxf(fmaxf(v0, v1), fmaxf(v2, v3));
            mx = fmaxf(mx, __shfl_xor(mx, 1));
            mx = fmaxf(mx, __shfl_xor(mx, 2));
            mx = fmaxf(mx, __shfl_xor(mx, 4));
            mx = fmaxf(mx, __shfl_xor(mx, 8));
            v0 = __expf(v0 - mx); v1 = __expf(v1 - mx);
            v2 = __expf(v2 - mx); v3 = __expf(v3 - mx);
          }
          er[0][r] = v0; er[1][r] = v1; er[2][r] = v2; er[3][r] = v3;
        }
        int n = rowA0 + wm * 64 + i * 16 + quad * 4;   // 4-aligned
        int bb = n >> 13, s = n & 8191;
        int bh2 = bb * NH_ + h;
#pragma unroll
        for (int j = 0; j < 4; ++j) {
          ushort4 o;
          o.x = f2b(er[j][0]); o.y = f2b(er[j][1]);
          o.z = f2b(er[j][2]); o.w = f2b(er[j][3]);
          *(ushort4*)&dstT[((size_t)bh2 * 64 + j * 16 + l16) * S_ + s] = o;
        }
      }
    }
  }
}

// ---------- K5: kv summary via MFMA: kvT[bh][d][m], row 64 = ksum ----------
__global__ __launch_bounds__(256, 4) void kv_accum_mfma(
    const U16* __restrict__ kpT, const U16* __restrict__ vT,
    float* __restrict__ kvT) {
  __shared__ __align__(16) U16 Us[2 * 64 * 64];   // [0:4096]=vT tile, [4096:8192]=kpT
  const int tid = threadIdx.x, w = tid >> 6, lane = tid & 63;
  const int quad = lane >> 4, l16 = lane & 15;
  const int bh = blockIdx.y;
  const int n0 = blockIdx.x * 512;
  const U16* srcs[4];
  unsigned ldsoff[4];
#pragma unroll
  for (int t = 0; t < 4; ++t) {
    int c = w * 4 + t, buf = c >> 3;              // 0..15; buf 0 = vT, 1 = kpT
    int r = (c & 7) * 8 + (lane >> 3);
    const U16* base = buf ? kpT : vT;
    srcs[t] = base + ((size_t)bh * 64 + r) * S_ + n0 + (lane & 7) * 8;
    ldsoff[t] = buf * 4096 + (c & 7) * 512;
  }
  f32x4 acc[4] = {};
  float ks[4] = {0.f, 0.f, 0.f, 0.f};
  for (int nc = 0; nc < 512; nc += 64) {
#pragma unroll
    for (int t = 0; t < 4; ++t) gl2lds16(srcs[t] + nc, &Us[ldsoff[t]]);
    __syncthreads();
#pragma unroll
    for (int k0 = 0; k0 < 64; k0 += 32) {
      bf16x8 av = *(const bf16x8*)&Us[(w * 16 + l16) * 64 + k0 + quad * 8];
#pragma unroll
      for (int j = 0; j < 4; ++j) {
        bf16x8 bk = *(const bf16x8*)&Us[4096 + (j * 16 + l16) * 64 + k0 + quad * 8];
        if (w == 0) {
#pragma unroll
          for (int e = 0; e < 8; ++e) ks[j] += b2f((U16)bk[e]);
        }
        acc[j] = __builtin_amdgcn_mfma_f32_16x16x32_bf16(av, bk, acc[j], 0, 0, 0);
      }
    }
    __syncthreads();
  }
#pragma unroll
  for (int j = 0; j < 4; ++j)
#pragma unroll
    for (int r = 0; r < 4; ++r) {
      int d = w * 16 + quad * 4 + r;
      atomicAdd(&kvT[((size_t)bh * 80 + d) * 64 + j * 16 + l16], acc[j][r]);
    }
  if (w == 0) {
#pragma unroll
    for (int j = 0; j < 4; ++j) {
      ks[j] += __shfl_xor(ks[j], 16);
      ks[j] += __shfl_xor(ks[j], 32);
    }
    if (lane < 16) {
#pragma unroll
      for (int j = 0; j < 4; ++j)
        atomicAdd(&kvT[((size_t)bh * 80 + 64) * 64 + j * 16 + lane], ks[j]);
    }
  }
}

// ---------- K7: fused ctx = (qp@kv)/(norm+eps) then out = ctx@Wo + bo -------
// 512 blocks of 64 s-rows, 256 threads (4 waves). Phase A: ctx[64][768] into
// LDS (qp/kvH fragments read direct from global/L2). Phase B: K=768 GEMM vs
// WoT with counted-vmcnt(4) dbuf staging, out cols in 6 tiles of 128.
#define CTXP 776   // padded ctx row stride (U16)
__global__ __launch_bounds__(256) void ctx_out(
    const U16* __restrict__ qp, const U16* __restrict__ kvH,
    const U16* __restrict__ WoTH, const float* __restrict__ bo,
    float* __restrict__ out) {
  extern __shared__ __align__(16) U16 smem[];
  U16* ctxL = smem;                  // [64][CTXP] = 49664 U16
  U16* WoTb = smem + 49664;          // [2][128][64] = 16384 U16
  const int tid = threadIdx.x, w = tid >> 6, lane = tid & 63;
  const int quad = lane >> 4, l16 = lane & 15;
  const int row0 = blockIdx.x * 64;
  const int bb = row0 >> 13, s0 = row0 & 8191;
  const int bh0 = bb * NH_;
  // ---- phase A: wave w owns ctx rows w*16 .. w*16+15
#pragma unroll
  for (int h = 0; h < 12; ++h) {
    size_t qb = ((size_t)(bh0 + h) * S_ + s0 + w * 16 + l16) * 64;
    bf16x8 a0 = *(const bf16x8*)&qp[qb + quad * 8];
    bf16x8 a1 = *(const bf16x8*)&qp[qb + 32 + quad * 8];
    const U16* kb = kvH + (size_t)(bh0 + h) * 5120;
    f32x4 acc[5] = {};
#pragma unroll
    for (int j = 0; j < 5; ++j) {
      bf16x8 b0 = *(const bf16x8*)&kb[(j * 16 + l16) * 64 + quad * 8];
      bf16x8 b1 = *(const bf16x8*)&kb[(j * 16 + l16) * 64 + 32 + quad * 8];
      acc[j] = __builtin_amdgcn_mfma_f32_16x16x32_bf16(a0, b0, acc[j], 0, 0, 0);
      acc[j] = __builtin_amdgcn_mfma_f32_16x16x32_bf16(a1, b1, acc[j], 0, 0, 0);
    }
#pragma unroll
    for (int r = 0; r < 4; ++r) {
      float nv = __shfl(acc[4][r], lane & 48);     // col 64 = ksum dot
      float inv = 1.f / (nv + EPS_);
      int srow = w * 16 + quad * 4 + r;
#pragma unroll
      for (int j = 0; j < 4; ++j)
        ctxL[srow * CTXP + h * 64 + j * 16 + l16] = f2b(acc[j][r] * inv);
    }
  }
  __syncthreads();
  // ---- phase B: out[row0..+64][0..768] = ctxL @ WoT^T + bo
  const int wm = w & 1, wn = w >> 1;
  const int kch = (((tid & 7) ^ ((tid >> 3) & 7)) * 8);
  auto stageW = [&](int tt, int bi) {              // tt = nt*12 + t
    int ntp = tt / 12, tp = tt - ntp * 12;
    const U16* src = WoTH + (size_t)(ntp * 128 + (tid >> 3)) * H_ + tp * 64 + kch;
    unsigned dst = (unsigned)bi * 8192u + (unsigned)tid * 8u;
#pragma unroll
    for (int k = 0; k < 4; ++k)
      gl2lds16(src + (size_t)(32 * k) * H_, &WoTb[dst + (unsigned)k * 2048u]);
  };
  stageW(0, 0);
  for (int nt = 0; nt < 6; ++nt) {
    f32x4 acc2[2][4] = {};
    for (int t = 0; t < 12; ++t) {
      int tt = nt * 12 + t;
      if (tt < 71) {
        stageW(tt + 1, (tt + 1) & 1);
        asm volatile("s_waitcnt vmcnt(4)" ::: "memory");
      } else {
        asm volatile("s_waitcnt vmcnt(0)" ::: "memory");
      }
      __builtin_amdgcn_sched_barrier(0);
      __builtin_amdgcn_s_barrier();
      __builtin_amdgcn_sched_barrier(0);
      const unsigned ab = (unsigned)(tt & 1) * 8192u;
      bf16x8 a2[2][2], b2[4][2];
#pragma unroll
      for (int i2 = 0; i2 < 2; ++i2)
#pragma unroll
        for (int ks = 0; ks < 2; ++ks)
          a2[i2][ks] = *(const bf16x8*)&ctxL[
              (wm * 32 + i2 * 16 + l16) * CTXP + t * 64 + ks * 32 + quad * 8];
#pragma unroll
      for (int j2 = 0; j2 < 4; ++j2)
#pragma unroll
        for (int ks = 0; ks < 2; ++ks)
          b2[j2][ks] = *(const bf16x8*)&WoTb[ab +
              (unsigned)((wn * 64 + j2 * 16 + l16) * 64 +
                         (((ks * 4 + quad) ^ (l16 & 7)) * 8))];
      asm volatile("s_waitcnt lgkmcnt(0)" ::: "memory");
      __builtin_amdgcn_sched_barrier(0);
      __builtin_amdgcn_s_setprio(1);
#pragma unroll
      for (int ks = 0; ks < 2; ++ks)
#pragma unroll
        for (int j2 = 0; j2 < 4; ++j2)
#pragma unroll
          for (int i2 = 0; i2 < 2; ++i2)
            acc2[i2][j2] = __builtin_amdgcn_mfma_f32_16x16x32_bf16(
                a2[i2][ks], b2[j2][ks], acc2[i2][j2], 0, 0, 0);
      __builtin_amdgcn_s_setprio(0);
      __builtin_amdgcn_sched_barrier(0);
      __builtin_amdgcn_s_barrier();
      __builtin_amdgcn_sched_barrier(0);
    }
    // epilogue for this col-tile (no LDS use; overlaps next stage)
#pragma unroll
    for (int i2 = 0; i2 < 2; ++i2) {
      int row = row0 + wm * 32 + i2 * 16 + quad * 4;
#pragma unroll
      for (int j2 = 0; j2 < 4; ++j2) {
        int col = nt * 128 + wn * 64 + j2 * 16 + l16;
        float bvv = bo[col];
#pragma unroll
        for (int r = 0; r < 4; ++r)
          out[(size_t)(row + r) * H_ + col] = acc2[i2][j2][r] + bvv;
      }
    }
  }
}

extern "C" void kernel_launch(void* const* d_in, const int* in_sizes, int n_in,
                              void* d_out, int out_size, void* d_ws, size_t ws_size,
                              hipStream_t stream) {
  const float* hs = (const float*)d_in[0];
  const float* Wq = (const float*)d_in[1];
  const float* bq = (const float*)d_in[2];
  const float* Wk = (const float*)d_in[3];
  const float* bk = (const float*)d_in[4];
  const float* Wv = (const float*)d_in[5];
  const float* bv = (const float*)d_in[6];
  const float* Wo = (const float*)d_in[7];
  const float* bo = (const float*)d_in[8];
  const float* P  = (const float*)d_in[9];
  float* out = (float*)d_out;

  char* ws = (char*)d_ws;
  size_t off = 0;
  auto alloc = [&](size_t bytes) -> void* {
    void* p = ws + off;
    off = (off + bytes + 255) & ~(size_t)255;
    return p;
  };
  U16*   hs_hi = (U16*)alloc(50331648);     // [32768,768] bf16
  float* WqpF  = (float*)alloc(2359296);
  float* WkpF  = (float*)alloc(2359296);
  float* bqpF  = (float*)alloc(3072);
  float* bkpF  = (float*)alloc(3072);
  U16*   WcatH = (U16*)alloc(3538944);      // [2304,768] bf16
  U16*   WoTH  = (U16*)alloc(1179648);
  float* biasC = (float*)alloc(9216);
  U16*   qp    = (U16*)alloc(50331648);     // [48,8192,64] bf16 row-major
  U16*   kpT   = (U16*)alloc(50331648);     // [48,64,8192] bf16 transposed
  U16*   vT    = (U16*)alloc(50331648);     // [48,64,8192] bf16 transposed
  float* kvT   = (float*)alloc(983040);     // [48,80,64] fp32 (row 64 = ksum)
  U16*   kvH   = (U16*)alloc(491520);       // [48,80,64] bf16

  zero_f32<<<dim3(960), dim3(256), 0, stream>>>(kvT, 245760);
  cvt_f32_bf16<<<dim3(24576), dim3(256), 0, stream>>>(hs, hs_hi, 6291456);
  fold_proj<<<dim3(192, 12, 2), dim3(256), 0, stream>>>(Wq, bq, Wk, bk, P, WqpF, bqpF, WkpF, bkpF);
  build_cat<<<dim3(3, 3072), dim3(256), 0, stream>>>(WqpF, WkpF, Wv, Wo, WcatH, WoTH);
  build_bias<<<dim3(9), dim3(256), 0, stream>>>(bqpF, bkpF, bv, biasC);
  gemm_qkv<<<dim3(512), dim3(256), 0, stream>>>(hs_hi, WcatH, biasC, qp, kpT, vT);
  kv_accum_mfma<<<dim3(16, 48), dim3(256), 0, stream>>>(kpT, vT, kvT);
  cvt_f32_bf16<<<dim3(240), dim3(256), 0, stream>>>(kvT, kvH, 61440);
  ctx_out<<<dim3(512), dim3(256), 132096, stream>>>(qp, kvH, WoTH, bo, out);
}